// Round 1
// baseline (120.747 us; speedup 1.0000x reference)
//
#include <hip/hip_runtime.h>
#include <stdint.h>

// RandomSelfAttention: B=2, S=4096, S2=2048, NH=8, H=64, NKEYS=64
// q:(B,S2,NH,H) f32, k/v:(B,S,NH,H) f32, idx:(B,S2,NKEYS) int
// out z:(B,S2,NH,H) f32
//
// MODEL (refit r2-r12, per-CU cycles, ADDITIVE): dur = VALU_issue(~42K) +
// lines/0.7 (~48K). Six structural overlap attempts failed (r5/r6 reg
// batches, r7 tier pin, r8 LDS-DMA, r11 2q/wave, r12 big blocks).
// Gather-line term is compulsory (fp16 slices = 2 lines/row, each line
// touched once).
// THIS ROUND (single variable vs r13-fdot2 baseline 114.4us): remove the
// DS pipe entirely. ~62 ds_bpermute/wave (all __shfl/__shfl_xor) replaced:
//  - off broadcast: key assignment flipped to g*8+it -> lane's 8 offsets
//    are contiguous idx entries, loaded directly as 2x int4 (L1 broadcast).
//  - all butterfly reduces: DPP (quad_perm xor1/xor2, row_half_mirror,
//    row_ror:8) + gfx950 permlane16/32_swap. All VALU pipe, ~2cy latency
//    vs ~40-60cy ds_bpermute, and no lgkmcnt on the critical path.
// Predict: dur 114 -> ~95 if DS chains were exposed; neutral => additive
// {VALU, lines} model is complete -> roofline.
//
// Lessons pinned: r3 = never hard-cap regs to 64 (750MB scratch spill);
// r5/r6/r7 = compiler pins to 64-VGPR tier, refuses big load batches;
// r8 = 32KB LDS/block chokes occupancy; r10 = pk_fma f16-accum phase 2
// regressed; r11 = 2 units/wave regressed; r12 = 1024-thr blocks neutral.
// Watch WRITE_SIZE (8MB = clean) for spills on any edit.
// Block swizzle: blockIdx%16 = (b,n) combo -> per-XCD L2 set ~2MB (fp16).

#define BB 2
#define SS 4096
#define S2V 2048
#define NHV 8
#define HV 64
#define NKV 64

typedef _Float16 half_t;
typedef _Float16 half8 __attribute__((ext_vector_type(8)));
typedef _Float16 half2t __attribute__((ext_vector_type(2)));

#define NE ((size_t)BB * SS * NHV * HV)   // 4,194,304 elements in k (and v)

// ---- DPP / permlane reduction helpers (all VALU pipe, zero DS ops) ----
// ctrl: 0xB1 = quad_perm[1,0,3,2] (xor1), 0x4E = quad_perm[2,3,0,1] (xor2),
// 0x141 = row_half_mirror (xor4-within-8), 0x128 = row_ror:8 (xor8 in row16)
template <int CTRL>
__device__ __forceinline__ float dpp_add(float x) {
    int y = __builtin_amdgcn_update_dpp(0, __float_as_int(x), CTRL, 0xf, 0xf, true);
    return x + __int_as_float(y);
}
template <int CTRL>
__device__ __forceinline__ float dpp_max(float x) {
    int y = __builtin_amdgcn_update_dpp(0, __float_as_int(x), CTRL, 0xf, 0xf, true);
    return fmaxf(x, __int_as_float(y));
}

#if __has_builtin(__builtin_amdgcn_permlane16_swap)
__device__ __forceinline__ float swap16_add(float x) {
    auto r = __builtin_amdgcn_permlane16_swap(__float_as_uint(x), __float_as_uint(x), false, false);
    return __uint_as_float(r[0]) + __uint_as_float(r[1]);
}
__device__ __forceinline__ float swap16_max(float x) {
    auto r = __builtin_amdgcn_permlane16_swap(__float_as_uint(x), __float_as_uint(x), false, false);
    return fmaxf(__uint_as_float(r[0]), __uint_as_float(r[1]));
}
#else
__device__ __forceinline__ float swap16_add(float x) { return x + __shfl_xor(x, 16, 64); }
__device__ __forceinline__ float swap16_max(float x) { return fmaxf(x, __shfl_xor(x, 16, 64)); }
#endif

#if __has_builtin(__builtin_amdgcn_permlane32_swap)
__device__ __forceinline__ float swap32_add(float x) {
    auto r = __builtin_amdgcn_permlane32_swap(__float_as_uint(x), __float_as_uint(x), false, false);
    return __uint_as_float(r[0]) + __uint_as_float(r[1]);
}
__device__ __forceinline__ float swap32_max(float x) {
    auto r = __builtin_amdgcn_permlane32_swap(__float_as_uint(x), __float_as_uint(x), false, false);
    return fmaxf(__uint_as_float(r[0]), __uint_as_float(r[1]));
}
#else
__device__ __forceinline__ float swap32_add(float x) { return x + __shfl_xor(x, 32, 64); }
__device__ __forceinline__ float swap32_max(float x) { return fmaxf(x, __shfl_xor(x, 32, 64)); }
#endif

// ---- prepass: k,v fp32 -> fp16 into workspace (coalesced stream) ----
__global__ __launch_bounds__(256)
void cvt_kernel(const float* __restrict__ k, const float* __restrict__ v,
                half_t* __restrict__ kh, half_t* __restrict__ vh) {
    const size_t base = ((size_t)blockIdx.x * 256 + threadIdx.x) * 8;
    const float* src; half_t* dst; size_t off;
    if (base < NE) { src = k; dst = kh; off = base; }
    else           { src = v; dst = vh; off = base - NE; }
    const float4 a = *(const float4*)(src + off);
    const float4 b = *(const float4*)(src + off + 4);
    half8 h = { (_Float16)a.x, (_Float16)a.y, (_Float16)a.z, (_Float16)a.w,
                (_Float16)b.x, (_Float16)b.y, (_Float16)b.z, (_Float16)b.w };
    *(half8*)(dst + off) = h;
}

// ---- main: fp16 gather, 1 query/wave. Lane = (g=lane>>3, hc=lane&7) ----
// iter it of group g handles key g*8+it (contiguous per group -> direct
// int4 idx loads, no off shuffles). Softmax/PV are key-permutation
// invariant, so output is identical to the it*8+g assignment.
__global__ __launch_bounds__(256)
void rsa_fp16_kernel(const float* __restrict__ q, const half_t* __restrict__ kh,
                     const half_t* __restrict__ vh, const int* __restrict__ idx,
                     float* __restrict__ out) {
    const int lane = threadIdx.x & 63;
    const int w    = threadIdx.x >> 6;
    const int bi   = blockIdx.x;

    const int combo = bi & 15;
    const int b     = combo >> 3;
    const int n     = combo & 7;
    const int qi    = ((bi >> 4) << 2) + w;

    const int g  = lane >> 3;    // key group 0..7
    const int hc = lane & 7;     // h-chunk 0..7 (half8 = 16B granularity)

    const size_t bq = (size_t)b * S2V + qi;

    // this group's 8 key offsets: contiguous idx entries, direct load
    const int* irow = idx + bq * NKV + g * 8;
    const int4 i0 = *(const int4*)(irow);
    const int4 i1 = *(const int4*)(irow + 4);
    int offs[8] = { i0.x * (NHV * HV), i0.y * (NHV * HV),
                    i0.z * (NHV * HV), i0.w * (NHV * HV),
                    i1.x * (NHV * HV), i1.y * (NHV * HV),
                    i1.z * (NHV * HV), i1.w * (NHV * HV) };

    // q chunk: 8 floats, prescaled by h^-0.5 = 1/8, converted to half8 once
    const float* qrow = q + (bq * NHV + n) * HV;
    const float4 qa = *(const float4*)(qrow + hc * 8);
    const float4 qb = *(const float4*)(qrow + hc * 8 + 4);
    const half8 qh = { (_Float16)(qa.x * 0.125f), (_Float16)(qa.y * 0.125f),
                       (_Float16)(qa.z * 0.125f), (_Float16)(qa.w * 0.125f),
                       (_Float16)(qb.x * 0.125f), (_Float16)(qb.y * 0.125f),
                       (_Float16)(qb.z * 0.125f), (_Float16)(qb.w * 0.125f) };
    const half2t* q2 = (const half2t*)&qh;

    const half_t* kb = kh + ((size_t)b * SS * NHV + n) * HV;
    const half_t* vb = vh + ((size_t)b * SS * NHV + n) * HV;

    // ---- phase 1: scores via fdot2; dot-reduce across hc via DPP ----
    float sc[8];
#pragma unroll
    for (int it = 0; it < 8; ++it) {
        const half8 kk = *(const half8*)(kb + offs[it] + hc * 8);
        float d = 0.f;
#if __has_builtin(__builtin_amdgcn_fdot2)
        const half2t* k2 = (const half2t*)&kk;
#pragma unroll
        for (int j = 0; j < 4; ++j)
            d = __builtin_amdgcn_fdot2(k2[j], q2[j], d, false);
#else
#pragma unroll
        for (int j = 0; j < 8; ++j) d = fmaf((float)kk[j], (float)qh[j], d);
#endif
        d = dpp_add<0xB1>(d);    // xor1  (quad_perm [1,0,3,2])
        d = dpp_add<0x4E>(d);    // xor2  (quad_perm [2,3,0,1])
        d = dpp_add<0x141>(d);   // xor4 within 8 (row_half_mirror)
        sc[it] = d;   // full dot of key g*8+it, replicated over 8-lane group
    }

    // ---- softmax over 64 keys (tree in-lane, DPP/permlane cross-lane) ----
    float m01 = fmaxf(sc[0], sc[1]), m23 = fmaxf(sc[2], sc[3]);
    float m45 = fmaxf(sc[4], sc[5]), m67 = fmaxf(sc[6], sc[7]);
    float m = fmaxf(fmaxf(m01, m23), fmaxf(m45, m67));
    m = dpp_max<0x128>(m);   // xor8 (row_ror:8)
    m = swap16_max(m);       // xor16 (permlane16_swap)
    m = swap32_max(m);       // xor32 (permlane32_swap)

    float s01, s23, s45, s67;
#pragma unroll
    for (int it = 0; it < 8; ++it) sc[it] = __expf(sc[it] - m);
    s01 = sc[0] + sc[1]; s23 = sc[2] + sc[3];
    s45 = sc[4] + sc[5]; s67 = sc[6] + sc[7];
    float ssum = (s01 + s23) + (s45 + s67);
    ssum = dpp_add<0x128>(ssum);
    ssum = swap16_add(ssum);
    ssum = swap32_add(ssum);
    const float rs = __frcp_rn(ssum);

    // ---- phase 2: z = sum_key p[key] * v_row[key] (scalar f32, 8 chains) ----
    float za[8] = {0.f, 0.f, 0.f, 0.f, 0.f, 0.f, 0.f, 0.f};
#pragma unroll
    for (int it = 0; it < 8; ++it) {
        const half8 vv = *(const half8*)(vb + offs[it] + hc * 8);
        const float p = sc[it];
#pragma unroll
        for (int j = 0; j < 8; ++j) za[j] = fmaf(p, (float)vv[j], za[j]);
    }
    // reduce partial z across the 8 key groups (VALU-only butterflies)
#pragma unroll
    for (int j = 0; j < 8; ++j) {
        za[j] = dpp_add<0x128>(za[j]);  // xor8
        za[j] = swap16_add(za[j]);      // xor16
        za[j] = swap32_add(za[j]);      // xor32
    }

    if (g == 0) {
        float* orow = out + (bq * NHV + n) * HV + hc * 8;
        float4 o1 = make_float4(za[0] * rs, za[1] * rs, za[2] * rs, za[3] * rs);
        float4 o2 = make_float4(za[4] * rs, za[5] * rs, za[6] * rs, za[7] * rs);
        *(float4*)(orow)     = o1;
        *(float4*)(orow + 4) = o2;
    }
}

// ---- fallback (proven round-6 fp32 path) if ws too small ----
__global__ __launch_bounds__(256)
void rsa_fp32_kernel(const float* __restrict__ q, const float* __restrict__ k,
                     const float* __restrict__ v, const int* __restrict__ idx,
                     float* __restrict__ out) {
    const int lane = threadIdx.x & 63;
    const int w    = threadIdx.x >> 6;
    const int bi   = blockIdx.x;
    const int combo = bi & 15;
    const int b     = combo >> 3;
    const int n     = combo & 7;
    const int qi    = ((bi >> 4) << 2) + w;
    const int g  = lane >> 4;
    const int hc = lane & 15;
    const size_t bq = (size_t)b * S2V + qi;
    const float* qrow = q + (bq * NHV + n) * HV;
    const float4 qv = *(const float4*)(qrow + hc * 4);
    const float4 q4 = make_float4(qv.x * 0.125f, qv.y * 0.125f,
                                  qv.z * 0.125f, qv.w * 0.125f);
    const int my_off = idx[bq * NKV + lane] * (NHV * HV);
    const float* kb = k + ((size_t)b * SS * NHV + n) * HV;
    const float* vb = v + ((size_t)b * SS * NHV + n) * HV;
    float sc[16];
#pragma unroll
    for (int it = 0; it < 16; ++it) {
        const int off = __shfl(my_off, it * 4 + g, 64);
        const float4 k4 = *(const float4*)(kb + off + hc * 4);
        float d = k4.x * q4.x + k4.y * q4.y + k4.z * q4.z + k4.w * q4.w;
        d += __shfl_xor(d, 1);
        d += __shfl_xor(d, 2);
        d += __shfl_xor(d, 4);
        d += __shfl_xor(d, 8);
        sc[it] = d;
    }
    float m = sc[0];
#pragma unroll
    for (int it = 1; it < 16; ++it) m = fmaxf(m, sc[it]);
    m = fmaxf(m, __shfl_xor(m, 16));
    m = fmaxf(m, __shfl_xor(m, 32));
    float ssum = 0.f;
#pragma unroll
    for (int it = 0; it < 16; ++it) { sc[it] = __expf(sc[it] - m); ssum += sc[it]; }
    ssum += __shfl_xor(ssum, 16);
    ssum += __shfl_xor(ssum, 32);
    const float rs = __frcp_rn(ssum);
    float4 z = make_float4(0.f, 0.f, 0.f, 0.f);
#pragma unroll
    for (int it = 0; it < 16; ++it) {
        const int off = __shfl(my_off, it * 4 + g, 64);
        const float4 v4 = *(const float4*)(vb + off + hc * 4);
        const float p = sc[it];
        z.x = fmaf(p, v4.x, z.x); z.y = fmaf(p, v4.y, z.y);
        z.z = fmaf(p, v4.z, z.z); z.w = fmaf(p, v4.w, z.w);
    }
    z.x += __shfl_xor(z.x, 16); z.y += __shfl_xor(z.y, 16);
    z.z += __shfl_xor(z.z, 16); z.w += __shfl_xor(z.w, 16);
    z.x += __shfl_xor(z.x, 32); z.y += __shfl_xor(z.y, 32);
    z.z += __shfl_xor(z.z, 32); z.w += __shfl_xor(z.w, 32);
    if (g == 0) {
        float4 zo = make_float4(z.x * rs, z.y * rs, z.z * rs, z.w * rs);
        *(float4*)(out + (bq * NHV + n) * HV + hc * 4) = zo;
    }
}

extern "C" void kernel_launch(void* const* d_in, const int* in_sizes, int n_in,
                              void* d_out, int out_size, void* d_ws, size_t ws_size,
                              hipStream_t stream) {
    const float* q   = (const float*)d_in[0];
    const float* k   = (const float*)d_in[1];
    const float* v   = (const float*)d_in[2];
    const int*   idx = (const int*)d_in[3];
    float*       out = (float*)d_out;

    const size_t need = 2 * NE * sizeof(half_t);   // 16.8 MB
    if (ws_size >= need) {
        half_t* kh = (half_t*)d_ws;
        half_t* vh = kh + NE;
        const int cvt_blocks = (int)(2 * NE / 8 / 256);   // 4096
        cvt_kernel<<<cvt_blocks, 256, 0, stream>>>(k, v, kh, vh);
        // 32768 units / 4 waves per block = 8192 blocks
        rsa_fp16_kernel<<<8192, 256, 0, stream>>>(q, kh, vh, idx, out);
    } else {
        const int blocks = BB * S2V * NHV / 4;             // 8192
        rsa_fp32_kernel<<<blocks, 256, 0, stream>>>(q, k, v, idx, out);
    }
}

// Round 2
// 119.977 us; speedup vs baseline: 1.0064x; 1.0064x over previous
//
#include <hip/hip_runtime.h>
#include <stdint.h>

// RandomSelfAttention: B=2, S=4096, S2=2048, NH=8, H=64, NKEYS=64
// q:(B,S2,NH,H) f32, k/v:(B,S,NH,H) f32, idx:(B,S2,NKEYS) int
// out z:(B,S2,NH,H) f32
//
// MODEL (refit r2-r14, per-CU cycles, ADDITIVE): dur = VALU_issue + lines/0.7.
// r14 CALIBRATED the VALU term: +45 VALU ops/wave => +6.3us measured
// (128 waves/CU x 2cy/op => ~0.1us per op/wave). DS pipe (ds_bpermute
// shuffles) is FREE — fully hidden under VALU. Never trade DS for VALU.
// Gather-line term is compulsory (fp16 slices = 2 lines/row, touched once).
// Six structural overlap attempts failed (r5/r6 reg batches, r7 tier pin,
// r8 LDS-DMA, r11 2q/wave, r12 big blocks). r14 DPP/permlane regressed.
//
// THIS ROUND (single variable vs r13 baseline 114.4us): phase 2 via
// v_fma_mix_f32 inline asm. r13's fdot2 win proved the compiler emits
// separate cvt_f32_f16 + fma_f32 for f16->f32 FMA patterns; phase 2 is
// the largest VALU block (8 it x 16 ops = 128/wave). fma_mix does
// za += p * fpext(vv.h16) in ONE op (op_sel picks lo/hi half), bit-identical
// numerics. 128 -> 64 ops/wave. Predict dur 114.4 -> ~107us; absmax
// unchanged; WRITE_SIZE stays 8MB (no spill). Neutral => compiler already
// mixed => VALU floor stands, audit disasm next.
//
// Lessons pinned: r3 = never hard-cap regs to 64 (750MB scratch spill);
// r5/r6/r7 = compiler pins to 64-VGPR tier, refuses big load batches;
// r8 = 32KB LDS/block chokes occupancy; r10 = pk_fma f16-accum phase 2
// regressed; r11 = 2 units/wave regressed; r12 = 1024-thr blocks neutral;
// r14 = DPP reduces + direct idx loads regressed (+40 VALU, DS was free).
// Watch WRITE_SIZE (8MB = clean) for spills on any edit.
// Block swizzle: blockIdx%16 = (b,n) combo -> per-XCD L2 set ~2MB (fp16).

#define BB 2
#define SS 4096
#define S2V 2048
#define NHV 8
#define HV 64
#define NKV 64

typedef _Float16 half_t;
typedef _Float16 half8 __attribute__((ext_vector_type(8)));
typedef _Float16 half2t __attribute__((ext_vector_type(2)));

#define NE ((size_t)BB * SS * NHV * HV)   // 4,194,304 elements in k (and v)

// ---- prepass: k,v fp32 -> fp16 into workspace (coalesced stream) ----
__global__ __launch_bounds__(256)
void cvt_kernel(const float* __restrict__ k, const float* __restrict__ v,
                half_t* __restrict__ kh, half_t* __restrict__ vh) {
    const size_t base = ((size_t)blockIdx.x * 256 + threadIdx.x) * 8;
    const float* src; half_t* dst; size_t off;
    if (base < NE) { src = k; dst = kh; off = base; }
    else           { src = v; dst = vh; off = base - NE; }
    const float4 a = *(const float4*)(src + off);
    const float4 b = *(const float4*)(src + off + 4);
    half8 h = { (_Float16)a.x, (_Float16)a.y, (_Float16)a.z, (_Float16)a.w,
                (_Float16)b.x, (_Float16)b.y, (_Float16)b.z, (_Float16)b.w };
    *(half8*)(dst + off) = h;
}

// ---- main: fp16 gather, 1 query/wave. Lane = (g=lane>>3, hc=lane&7) ----
__global__ __launch_bounds__(256)
void rsa_fp16_kernel(const float* __restrict__ q, const half_t* __restrict__ kh,
                     const half_t* __restrict__ vh, const int* __restrict__ idx,
                     float* __restrict__ out) {
    const int lane = threadIdx.x & 63;
    const int w    = threadIdx.x >> 6;
    const int bi   = blockIdx.x;

    const int combo = bi & 15;
    const int b     = combo >> 3;
    const int n     = combo & 7;
    const int qi    = ((bi >> 4) << 2) + w;

    const int g  = lane >> 3;    // key group 0..7
    const int hc = lane & 7;     // h-chunk 0..7 (half8 = 16B granularity)

    const size_t bq = (size_t)b * S2V + qi;

    // q chunk: 8 floats, prescaled by h^-0.5 = 1/8, converted to half8 once
    const float* qrow = q + (bq * NHV + n) * HV;
    const float4 qa = *(const float4*)(qrow + hc * 8);
    const float4 qb = *(const float4*)(qrow + hc * 8 + 4);
    const half8 qh = { (_Float16)(qa.x * 0.125f), (_Float16)(qa.y * 0.125f),
                       (_Float16)(qa.z * 0.125f), (_Float16)(qa.w * 0.125f),
                       (_Float16)(qb.x * 0.125f), (_Float16)(qb.y * 0.125f),
                       (_Float16)(qb.z * 0.125f), (_Float16)(qb.w * 0.125f) };
    const half2t* q2 = (const half2t*)&qh;

    const int my_off = idx[bq * NKV + lane] * (NHV * HV);

    const half_t* kb = kh + ((size_t)b * SS * NHV + n) * HV;
    const half_t* vb = vh + ((size_t)b * SS * NHV + n) * HV;

    // ---- phase 1: scores via fdot2. iter it covers keys it*8 + g ----
    int   offs[8];
    float sc[8];
#pragma unroll
    for (int it = 0; it < 8; ++it) {
        const int off = __shfl(my_off, it * 8 + g, 64);
        offs[it] = off;
        const half8 kk = *(const half8*)(kb + off + hc * 8);
        float d = 0.f;
#if __has_builtin(__builtin_amdgcn_fdot2)
        const half2t* k2 = (const half2t*)&kk;
#pragma unroll
        for (int j = 0; j < 4; ++j)
            d = __builtin_amdgcn_fdot2(k2[j], q2[j], d, false);
#else
#pragma unroll
        for (int j = 0; j < 8; ++j) d = fmaf((float)kk[j], (float)qh[j], d);
#endif
        d += __shfl_xor(d, 1);
        d += __shfl_xor(d, 2);
        d += __shfl_xor(d, 4);
        sc[it] = d;   // full dot of key it*8+g, replicated over 8-lane group
    }

    // ---- softmax over 64 keys ----
    float m = sc[0];
#pragma unroll
    for (int it = 1; it < 8; ++it) m = fmaxf(m, sc[it]);
    m = fmaxf(m, __shfl_xor(m, 8));
    m = fmaxf(m, __shfl_xor(m, 16));
    m = fmaxf(m, __shfl_xor(m, 32));

    float ssum = 0.f;
#pragma unroll
    for (int it = 0; it < 8; ++it) {
        sc[it] = __expf(sc[it] - m);
        ssum += sc[it];
    }
    ssum += __shfl_xor(ssum, 8);
    ssum += __shfl_xor(ssum, 16);
    ssum += __shfl_xor(ssum, 32);
    const float rs = __frcp_rn(ssum);

    // ---- phase 2: z = sum_key p[key] * v_row[key] ----
    // v_fma_mix_f32: za(f32) += p(f32) * fpext(v.h16) in one VALU op.
    // op_sel_hi:[0,1,0] marks src1 as f16; op_sel:[0,1,0] picks the hi half.
    // Bit-identical to cvt_f32_f16 + fma_f32, at half the issue count.
    float za[8] = {0.f, 0.f, 0.f, 0.f, 0.f, 0.f, 0.f, 0.f};
#pragma unroll
    for (int it = 0; it < 8; ++it) {
        const uint4 vv = *(const uint4*)(vb + offs[it] + hc * 8);
        const float p = sc[it];
        const uint32_t vw[4] = { vv.x, vv.y, vv.z, vv.w };
#pragma unroll
        for (int j = 0; j < 4; ++j) {
            asm("v_fma_mix_f32 %0, %1, %2, %0 op_sel_hi:[0,1,0]"
                : "+v"(za[2 * j]) : "v"(p), "v"(vw[j]));
            asm("v_fma_mix_f32 %0, %1, %2, %0 op_sel:[0,1,0] op_sel_hi:[0,1,0]"
                : "+v"(za[2 * j + 1]) : "v"(p), "v"(vw[j]));
        }
    }
    // reduce partial z across the 8 key groups
#pragma unroll
    for (int j = 0; j < 8; ++j) {
        za[j] += __shfl_xor(za[j], 8);
        za[j] += __shfl_xor(za[j], 16);
        za[j] += __shfl_xor(za[j], 32);
    }

    if (g == 0) {
        float* orow = out + (bq * NHV + n) * HV + hc * 8;
        float4 o1 = make_float4(za[0] * rs, za[1] * rs, za[2] * rs, za[3] * rs);
        float4 o2 = make_float4(za[4] * rs, za[5] * rs, za[6] * rs, za[7] * rs);
        *(float4*)(orow)     = o1;
        *(float4*)(orow + 4) = o2;
    }
}

// ---- fallback (proven round-6 fp32 path) if ws too small ----
__global__ __launch_bounds__(256)
void rsa_fp32_kernel(const float* __restrict__ q, const float* __restrict__ k,
                     const float* __restrict__ v, const int* __restrict__ idx,
                     float* __restrict__ out) {
    const int lane = threadIdx.x & 63;
    const int w    = threadIdx.x >> 6;
    const int bi   = blockIdx.x;
    const int combo = bi & 15;
    const int b     = combo >> 3;
    const int n     = combo & 7;
    const int qi    = ((bi >> 4) << 2) + w;
    const int g  = lane >> 4;
    const int hc = lane & 15;
    const size_t bq = (size_t)b * S2V + qi;
    const float* qrow = q + (bq * NHV + n) * HV;
    const float4 qv = *(const float4*)(qrow + hc * 4);
    const float4 q4 = make_float4(qv.x * 0.125f, qv.y * 0.125f,
                                  qv.z * 0.125f, qv.w * 0.125f);
    const int my_off = idx[bq * NKV + lane] * (NHV * HV);
    const float* kb = k + ((size_t)b * SS * NHV + n) * HV;
    const float* vb = v + ((size_t)b * SS * NHV + n) * HV;
    float sc[16];
#pragma unroll
    for (int it = 0; it < 16; ++it) {
        const int off = __shfl(my_off, it * 4 + g, 64);
        const float4 k4 = *(const float4*)(kb + off + hc * 4);
        float d = k4.x * q4.x + k4.y * q4.y + k4.z * q4.z + k4.w * q4.w;
        d += __shfl_xor(d, 1);
        d += __shfl_xor(d, 2);
        d += __shfl_xor(d, 4);
        d += __shfl_xor(d, 8);
        sc[it] = d;
    }
    float m = sc[0];
#pragma unroll
    for (int it = 1; it < 16; ++it) m = fmaxf(m, sc[it]);
    m = fmaxf(m, __shfl_xor(m, 16));
    m = fmaxf(m, __shfl_xor(m, 32));
    float ssum = 0.f;
#pragma unroll
    for (int it = 0; it < 16; ++it) { sc[it] = __expf(sc[it] - m); ssum += sc[it]; }
    ssum += __shfl_xor(ssum, 16);
    ssum += __shfl_xor(ssum, 32);
    const float rs = __frcp_rn(ssum);
    float4 z = make_float4(0.f, 0.f, 0.f, 0.f);
#pragma unroll
    for (int it = 0; it < 16; ++it) {
        const int off = __shfl(my_off, it * 4 + g, 64);
        const float4 v4 = *(const float4*)(vb + off + hc * 4);
        const float p = sc[it];
        z.x = fmaf(p, v4.x, z.x); z.y = fmaf(p, v4.y, z.y);
        z.z = fmaf(p, v4.z, z.z); z.w = fmaf(p, v4.w, z.w);
    }
    z.x += __shfl_xor(z.x, 16); z.y += __shfl_xor(z.y, 16);
    z.z += __shfl_xor(z.z, 16); z.w += __shfl_xor(z.w, 16);
    z.x += __shfl_xor(z.x, 32); z.y += __shfl_xor(z.y, 32);
    z.z += __shfl_xor(z.z, 32); z.w += __shfl_xor(z.w, 32);
    if (g == 0) {
        float4 zo = make_float4(z.x * rs, z.y * rs, z.z * rs, z.w * rs);
        *(float4*)(out + (bq * NHV + n) * HV + hc * 4) = zo;
    }
}

extern "C" void kernel_launch(void* const* d_in, const int* in_sizes, int n_in,
                              void* d_out, int out_size, void* d_ws, size_t ws_size,
                              hipStream_t stream) {
    const float* q   = (const float*)d_in[0];
    const float* k   = (const float*)d_in[1];
    const float* v   = (const float*)d_in[2];
    const int*   idx = (const int*)d_in[3];
    float*       out = (float*)d_out;

    const size_t need = 2 * NE * sizeof(half_t);   // 16.8 MB
    if (ws_size >= need) {
        half_t* kh = (half_t*)d_ws;
        half_t* vh = kh + NE;
        const int cvt_blocks = (int)(2 * NE / 8 / 256);   // 4096
        cvt_kernel<<<cvt_blocks, 256, 0, stream>>>(k, v, kh, vh);
        // 32768 units / 4 waves per block = 8192 blocks
        rsa_fp16_kernel<<<8192, 256, 0, stream>>>(q, kh, vh, idx, out);
    } else {
        const int blocks = BB * S2V * NHV / 4;             // 8192
        rsa_fp32_kernel<<<blocks, 256, 0, stream>>>(q, k, v, idx, out);
    }
}

// Round 3
// 115.210 us; speedup vs baseline: 1.0481x; 1.0414x over previous
//
#include <hip/hip_runtime.h>
#include <stdint.h>

// RandomSelfAttention: B=2, S=4096, S2=2048, NH=8, H=64, NKEYS=64
// q:(B,S2,NH,H) f32, k/v:(B,S,NH,H) f32, idx:(B,S2,NKEYS) int
// out z:(B,S2,NH,H) f32
//
// MODEL (REVISED r16): dur_us is the graph SUM, not one dispatch:
//   dur = 2 x 42.5us  (harness ws re-poison: 256MiB fills @ 6.3TB/s HBM
//                      write BW — FIXED, not ours; rocprof top-5 is all
//                      fillBufferAligned, rsa never appears => rsa < 42us)
//       + ~8us        (cvt: 50MB @ HBM BW floor)
//       + ~21us       (rsa: 512MB L2 gather-line traffic @ ~25-35TB/s;
//                      VALU ~8.5us hides under it)
//   85 + 8 + 21 = 114 = r13's measurement. Both BW terms are at floor.
// r14 (DPP, +40 VALU) and r15 (fma_mix asm, -64 VALU) both landed ~120:
// opposite VALU deltas, same result — VALU is NOT the binding term
// (it's hidden under the L2 gather). Regressions were either scheduling
// damage (asm ties / DPP chains) or ~±6us cross-round noise.
// THIS ROUND: exact r13 revert (proven 114.4us) = noise calibration +
// floor confirmation. If ~114 reproduces, next call is ROOFLINE.
//
// Lessons pinned: r3 = never hard-cap regs to 64 (750MB scratch spill);
// r5/r6/r7 = compiler pins to 64-VGPR tier, refuses big load batches;
// r8 = 32KB LDS/block chokes occupancy; r10 = pk_fma f16-accum phase 2
// regressed; r11 = 2 units/wave regressed; r12 = 1024-thr blocks neutral;
// r14 = DPP reduces + direct idx loads regressed (DS shuffles are free);
// r15 = inline-asm fma_mix regressed (asm reg-ties defeat the scheduler;
// VALU issue count is not the bottleneck anyway).
// Watch WRITE_SIZE (8MB = clean) for spills on any edit.
// Block swizzle: blockIdx%16 = (b,n) combo -> per-XCD L2 set ~2MB (fp16).

#define BB 2
#define SS 4096
#define S2V 2048
#define NHV 8
#define HV 64
#define NKV 64

typedef _Float16 half_t;
typedef _Float16 half8 __attribute__((ext_vector_type(8)));
typedef _Float16 half2t __attribute__((ext_vector_type(2)));

#define NE ((size_t)BB * SS * NHV * HV)   // 4,194,304 elements in k (and v)

// ---- prepass: k,v fp32 -> fp16 into workspace (coalesced stream) ----
__global__ __launch_bounds__(256)
void cvt_kernel(const float* __restrict__ k, const float* __restrict__ v,
                half_t* __restrict__ kh, half_t* __restrict__ vh) {
    const size_t base = ((size_t)blockIdx.x * 256 + threadIdx.x) * 8;
    const float* src; half_t* dst; size_t off;
    if (base < NE) { src = k; dst = kh; off = base; }
    else           { src = v; dst = vh; off = base - NE; }
    const float4 a = *(const float4*)(src + off);
    const float4 b = *(const float4*)(src + off + 4);
    half8 h = { (_Float16)a.x, (_Float16)a.y, (_Float16)a.z, (_Float16)a.w,
                (_Float16)b.x, (_Float16)b.y, (_Float16)b.z, (_Float16)b.w };
    *(half8*)(dst + off) = h;
}

// ---- main: fp16 gather, 1 query/wave. Lane = (g=lane>>3, hc=lane&7) ----
__global__ __launch_bounds__(256)
void rsa_fp16_kernel(const float* __restrict__ q, const half_t* __restrict__ kh,
                     const half_t* __restrict__ vh, const int* __restrict__ idx,
                     float* __restrict__ out) {
    const int lane = threadIdx.x & 63;
    const int w    = threadIdx.x >> 6;
    const int bi   = blockIdx.x;

    const int combo = bi & 15;
    const int b     = combo >> 3;
    const int n     = combo & 7;
    const int qi    = ((bi >> 4) << 2) + w;

    const int g  = lane >> 3;    // key group 0..7
    const int hc = lane & 7;     // h-chunk 0..7 (half8 = 16B granularity)

    const size_t bq = (size_t)b * S2V + qi;

    // q chunk: 8 floats, prescaled by h^-0.5 = 1/8, converted to half8 once
    const float* qrow = q + (bq * NHV + n) * HV;
    const float4 qa = *(const float4*)(qrow + hc * 8);
    const float4 qb = *(const float4*)(qrow + hc * 8 + 4);
    const half8 qh = { (_Float16)(qa.x * 0.125f), (_Float16)(qa.y * 0.125f),
                       (_Float16)(qa.z * 0.125f), (_Float16)(qa.w * 0.125f),
                       (_Float16)(qb.x * 0.125f), (_Float16)(qb.y * 0.125f),
                       (_Float16)(qb.z * 0.125f), (_Float16)(qb.w * 0.125f) };
    const half2t* q2 = (const half2t*)&qh;

    const int my_off = idx[bq * NKV + lane] * (NHV * HV);

    const half_t* kb = kh + ((size_t)b * SS * NHV + n) * HV;
    const half_t* vb = vh + ((size_t)b * SS * NHV + n) * HV;

    // ---- phase 1: scores via fdot2. iter it covers keys it*8 + g ----
    int   offs[8];
    float sc[8];
#pragma unroll
    for (int it = 0; it < 8; ++it) {
        const int off = __shfl(my_off, it * 8 + g, 64);
        offs[it] = off;
        const half8 kk = *(const half8*)(kb + off + hc * 8);
        float d = 0.f;
#if __has_builtin(__builtin_amdgcn_fdot2)
        const half2t* k2 = (const half2t*)&kk;
#pragma unroll
        for (int j = 0; j < 4; ++j)
            d = __builtin_amdgcn_fdot2(k2[j], q2[j], d, false);
#else
#pragma unroll
        for (int j = 0; j < 8; ++j) d = fmaf((float)kk[j], (float)qh[j], d);
#endif
        d += __shfl_xor(d, 1);
        d += __shfl_xor(d, 2);
        d += __shfl_xor(d, 4);
        sc[it] = d;   // full dot of key it*8+g, replicated over 8-lane group
    }

    // ---- softmax over 64 keys ----
    float m = sc[0];
#pragma unroll
    for (int it = 1; it < 8; ++it) m = fmaxf(m, sc[it]);
    m = fmaxf(m, __shfl_xor(m, 8));
    m = fmaxf(m, __shfl_xor(m, 16));
    m = fmaxf(m, __shfl_xor(m, 32));

    float ssum = 0.f;
#pragma unroll
    for (int it = 0; it < 8; ++it) {
        sc[it] = __expf(sc[it] - m);
        ssum += sc[it];
    }
    ssum += __shfl_xor(ssum, 8);
    ssum += __shfl_xor(ssum, 16);
    ssum += __shfl_xor(ssum, 32);
    const float rs = __frcp_rn(ssum);

    // ---- phase 2: z = sum_key p[key] * v_row[key] (scalar f32, 8 chains) ----
    float za[8] = {0.f, 0.f, 0.f, 0.f, 0.f, 0.f, 0.f, 0.f};
#pragma unroll
    for (int it = 0; it < 8; ++it) {
        const half8 vv = *(const half8*)(vb + offs[it] + hc * 8);
        const float p = sc[it];
#pragma unroll
        for (int j = 0; j < 8; ++j) za[j] = fmaf(p, (float)vv[j], za[j]);
    }
    // reduce partial z across the 8 key groups
#pragma unroll
    for (int j = 0; j < 8; ++j) {
        za[j] += __shfl_xor(za[j], 8);
        za[j] += __shfl_xor(za[j], 16);
        za[j] += __shfl_xor(za[j], 32);
    }

    if (g == 0) {
        float* orow = out + (bq * NHV + n) * HV + hc * 8;
        float4 o1 = make_float4(za[0] * rs, za[1] * rs, za[2] * rs, za[3] * rs);
        float4 o2 = make_float4(za[4] * rs, za[5] * rs, za[6] * rs, za[7] * rs);
        *(float4*)(orow)     = o1;
        *(float4*)(orow + 4) = o2;
    }
}

// ---- fallback (proven round-6 fp32 path) if ws too small ----
__global__ __launch_bounds__(256)
void rsa_fp32_kernel(const float* __restrict__ q, const float* __restrict__ k,
                     const float* __restrict__ v, const int* __restrict__ idx,
                     float* __restrict__ out) {
    const int lane = threadIdx.x & 63;
    const int w    = threadIdx.x >> 6;
    const int bi   = blockIdx.x;
    const int combo = bi & 15;
    const int b     = combo >> 3;
    const int n     = combo & 7;
    const int qi    = ((bi >> 4) << 2) + w;
    const int g  = lane >> 4;
    const int hc = lane & 15;
    const size_t bq = (size_t)b * S2V + qi;
    const float* qrow = q + (bq * NHV + n) * HV;
    const float4 qv = *(const float4*)(qrow + hc * 4);
    const float4 q4 = make_float4(qv.x * 0.125f, qv.y * 0.125f,
                                  qv.z * 0.125f, qv.w * 0.125f);
    const int my_off = idx[bq * NKV + lane] * (NHV * HV);
    const float* kb = k + ((size_t)b * SS * NHV + n) * HV;
    const float* vb = v + ((size_t)b * SS * NHV + n) * HV;
    float sc[16];
#pragma unroll
    for (int it = 0; it < 16; ++it) {
        const int off = __shfl(my_off, it * 4 + g, 64);
        const float4 k4 = *(const float4*)(kb + off + hc * 4);
        float d = k4.x * q4.x + k4.y * q4.y + k4.z * q4.z + k4.w * q4.w;
        d += __shfl_xor(d, 1);
        d += __shfl_xor(d, 2);
        d += __shfl_xor(d, 4);
        d += __shfl_xor(d, 8);
        sc[it] = d;
    }
    float m = sc[0];
#pragma unroll
    for (int it = 1; it < 16; ++it) m = fmaxf(m, sc[it]);
    m = fmaxf(m, __shfl_xor(m, 16));
    m = fmaxf(m, __shfl_xor(m, 32));
    float ssum = 0.f;
#pragma unroll
    for (int it = 0; it < 16; ++it) { sc[it] = __expf(sc[it] - m); ssum += sc[it]; }
    ssum += __shfl_xor(ssum, 16);
    ssum += __shfl_xor(ssum, 32);
    const float rs = __frcp_rn(ssum);
    float4 z = make_float4(0.f, 0.f, 0.f, 0.f);
#pragma unroll
    for (int it = 0; it < 16; ++it) {
        const int off = __shfl(my_off, it * 4 + g, 64);
        const float4 v4 = *(const float4*)(vb + off + hc * 4);
        const float p = sc[it];
        z.x = fmaf(p, v4.x, z.x); z.y = fmaf(p, v4.y, z.y);
        z.z = fmaf(p, v4.z, z.z); z.w = fmaf(p, v4.w, z.w);
    }
    z.x += __shfl_xor(z.x, 16); z.y += __shfl_xor(z.y, 16);
    z.z += __shfl_xor(z.z, 16); z.w += __shfl_xor(z.w, 16);
    z.x += __shfl_xor(z.x, 32); z.y += __shfl_xor(z.y, 32);
    z.z += __shfl_xor(z.z, 32); z.w += __shfl_xor(z.w, 32);
    if (g == 0) {
        float4 zo = make_float4(z.x * rs, z.y * rs, z.z * rs, z.w * rs);
        *(float4*)(out + (bq * NHV + n) * HV + hc * 4) = zo;
    }
}

extern "C" void kernel_launch(void* const* d_in, const int* in_sizes, int n_in,
                              void* d_out, int out_size, void* d_ws, size_t ws_size,
                              hipStream_t stream) {
    const float* q   = (const float*)d_in[0];
    const float* k   = (const float*)d_in[1];
    const float* v   = (const float*)d_in[2];
    const int*   idx = (const int*)d_in[3];
    float*       out = (float*)d_out;

    const size_t need = 2 * NE * sizeof(half_t);   // 16.8 MB
    if (ws_size >= need) {
        half_t* kh = (half_t*)d_ws;
        half_t* vh = kh + NE;
        const int cvt_blocks = (int)(2 * NE / 8 / 256);   // 4096
        cvt_kernel<<<cvt_blocks, 256, 0, stream>>>(k, v, kh, vh);
        // 32768 units / 4 waves per block = 8192 blocks
        rsa_fp16_kernel<<<8192, 256, 0, stream>>>(q, kh, vh, idx, out);
    } else {
        const int blocks = BB * S2V * NHV / 4;             // 8192
        rsa_fp32_kernel<<<blocks, 256, 0, stream>>>(q, k, v, idx, out);
    }
}